// Round 11
// baseline (2329.471 us; speedup 1.0000x reference)
//
#include <hip/hip_runtime.h>

// LSTM last-hidden + projection. B=256, T=4096, F=32, H=128, 4H=512.
// 64 WGs x 512 threads (8 waves, 2/SIMD, 1 WG/CU); WG g owns batches [4g,4g+4)
// at MFMA A-rows {0,4,8,12}. z(4x512) = [x_t|h](4x160) @ [W;U](160x512),
// mfma 16x16x32 f16.
// Model: makespan = 4096 x t_step. t_step ~1204cy (R14) = matrix-pipe 776
// (40 mfma/SIMD @ ~19.4cy) + ~428 serial head/tail. Serial-tail instr ~25cy.
// MFMA C-operand dep latency <= 155cy (m119: chain-2..8 at 8 waves/SIMD =
// 155cy spacing runs at 99.8% peak).
// HARD RULES (4 regressions' worth):
//  - step body BRANCH-FREE, no exec-mask dance (R11 +193cy; R14 -180cy);
//  - loop-carried regs written UNCONDITIONALLY only (R12 +265cy);
//  - no dependent MFMA pair closer than ~155cy (R6; m119 bound).
// History: R5 2890; R6 REGRESS; R7 2780 (log2e fold); R8 3600 (copy tax);
// R9 2455 (ping-pong accX in ds_read shadow); R10 2371 (gate perm + fold);
// R11 3160 REGRESS (branches); R12 2824 REGRESS (masked carried writes);
// R13 2363 (csn-spine reassoc); R14 2056 = BEST (unconditional x-load,
// no exec-mask, cx ping-pong via macro args).
// R15 (this): depth-4 accumulation chain per gate (seeded accX), replacing
// two depth-2 chains + VALU join. Tail: 8 AGPR reads + 4 adds -> 4 reads;
// z->act spine one level shorter. Same-gate link spacing = 4 wave-slots
// (~155cy with co-wave) = m119-verified safe. Chain MFMA count unchanged.

#define TT 4096
#define FF 32
#define HH 128
#define NG 512

typedef float f32x4 __attribute__((ext_vector_type(4)));
typedef _Float16 h16x8 __attribute__((ext_vector_type(8)));

#if __has_builtin(__builtin_amdgcn_exp2f)
#define EX2(v) __builtin_amdgcn_exp2f(v)
#else
#define EX2(v) exp2f(v)
#endif
#define RCP(v) __builtin_amdgcn_rcpf(v)

__global__ __launch_bounds__(512, 2)
void lstm_seq_kernel(const float* __restrict__ x,        // (B,T,F)
                     const int*   __restrict__ seq_lens, // (B)
                     const float* __restrict__ W,        // (F,4H)
                     const float* __restrict__ U,        // (H,4H)
                     const float* __restrict__ bias,     // (4H)
                     const float* __restrict__ Wf,       // (H)
                     const float* __restrict__ bfp,      // (1)
                     float* __restrict__ out)            // (B)
{
    // h-only A staging: A[par][kc-1][slot][j] == A[m=slot&15][k=kc*32+(slot>>4)*8+j]
    __shared__ _Float16 A[2][4][64][8];
    __shared__ float outAcc[4];

    const int tid  = threadIdx.x;
    const int lane = tid & 63;
    const int w    = tid >> 6;     // wave 0..7
    const int c    = lane & 15;    // n-col within tile
    const int q    = lane >> 4;    // quad 0..3 -> this lane's batch
    const int b0   = blockIdx.x * 4;
    const int hc   = w * 16 + c;   // this lane's LSTM cell (0..127)

    {
        _Float16* p = &A[0][0][0][0];
        for (int i = tid; i < 2 * 4 * 64 * 8; i += 512) p[i] = (_Float16)0.f;
        if (tid < 4) outAcc[tid] = 0.f;
    }

    const int sl0 = seq_lens[b0 + 0], sl1 = seq_lens[b0 + 1];
    const int sl2 = seq_lens[b0 + 2], sl3 = seq_lens[b0 + 3];
    const int gmax = max(max(sl0, sl1), max(sl2, sl3));
    const int slq  = seq_lens[b0 + q];

    const float L2E = 1.44269504f;      // log2(e)
    const float K2  = 2.88539008f;      // 2*log2(e)

    // gate issue order per level: g first (longest act chain), o last
    const int JP[4] = {2, 0, 1, 3};

    // register-resident weights: wave w -> tiles {8j+w}, j = gate i,f,g,o; n = j*128+hc
    // B-frag: lane holds B[k = kc*32 + q*8 + e][n]
    // Columns pre-scaled: i,f,o by -L2E (sigmoid via bare exp2), g by +2*L2E.
    h16x8 bh[4][5];
    #pragma unroll
    for (int j = 0; j < 4; ++j) {
        const int n = j * 128 + hc;
        const float gsc = (j == 2) ? K2 : -L2E;
        #pragma unroll
        for (int kc = 0; kc < 5; ++kc) {
            #pragma unroll
            for (int e = 0; e < 8; ++e) {
                const int k = kc * 32 + q * 8 + e;
                float v = (k < FF) ? W[k * NG + n] : U[(k - FF) * NG + n];
                bh[j][kc][e] = (_Float16)(v * gsc);
            }
        }
    }

    // bias folded into accX's C operand (only element [0] is ever read), pre-scaled
    f32x4 biasC[4];
    #pragma unroll
    for (int j = 0; j < 4; ++j) {
        const float gsc = (j == 2) ? K2 : -L2E;
        const float bv = bias[j * HH + hc] * gsc;
        f32x4 t = {bv, bv, bv, bv};
        biasC[j] = t;
    }
    const float wfv = Wf[hc];
    const int kk    = FF + hc;                        // K-position of this h element
    const int wkc   = (kk >> 5) - 1;                  // 0..3
    const int wslot = ((kk >> 3) & 3) * 16 + 4 * q;   // batch q at row 4q
    const int wj    = kk & 7;

    // x A-fragment: lane supplies A[m=c][k=q*8+e]; rows m%4!=0 are never read,
    // and xrow is a VALID address for every lane (batch c>>2 in [0,4)) ->
    // loads are UNCONDITIONAL (no branch, no exec-mask dance).
    const float* xrow = x + (size_t)(b0 + (c >> 2)) * TT * FF + q * 8;

    // ---- software pipeline state (no copies anywhere; double ping-pong) ----
    // accXa/accXb : z_x for alternating steps
    // xf_next     : cvt(x_{t+1}), feeds the head-issued z_x(t+1)
    // cx0/cx1     : raw x_{t+2} ping-pong pairs (written unconditionally)
    f32x4 accXa[4], accXb[4];
    h16x8 xf_next;
    {
        float4 xa = *(const float4*)(xrow);
        float4 xb = *(const float4*)(xrow + 4);
        h16x8 xf = { (_Float16)xa.x, (_Float16)xa.y, (_Float16)xa.z, (_Float16)xa.w,
                     (_Float16)xb.x, (_Float16)xb.y, (_Float16)xb.z, (_Float16)xb.w };
        #pragma unroll
        for (int j = 0; j < 4; ++j)
            accXa[j] = __builtin_amdgcn_mfma_f32_16x16x32_f16(xf, bh[j][0], biasC[j], 0, 0, 0);
    }
    {
        const float* p = xrow + (size_t)1 * FF;   // x_1
        float4 ya = *(const float4*)(p);
        float4 yb = *(const float4*)(p + 4);
        xf_next = (h16x8){ (_Float16)ya.x, (_Float16)ya.y, (_Float16)ya.z, (_Float16)ya.w,
                           (_Float16)yb.x, (_Float16)yb.y, (_Float16)yb.z, (_Float16)yb.w };
    }
    float4 cx0a, cx0b;                           // x_2 (pair 0)
    {
        const float* p = xrow + (size_t)2 * FF;
        cx0a = *(const float4*)(p);
        cx0b = *(const float4*)(p + 4);
    }
    float4 cx1a = {0,0,0,0}, cx1b = {0,0,0,0};   // pair 1: written in step 0 before read
    __syncthreads();

    float cs = 0.f, hh = 0.f;   // cs = 2*log2e * c  (pre-scaled cell state)

    // One LSTM step. PAR compile-time. AXIN consumed as depth-4 chain seed;
    // AXOUT (z_x for next step) + xf_next rotation + unconditional x-load all
    // issued at the HEAD inside the ds_read shadow. Per gate ONE depth-4
    // accumulation chain (levels rotate gates: same-gate spacing ~155cy).
    // Tail = 4 AGPR reads + act + selects + ds_write. BRANCH-FREE body.
#define LSTM_STEP(PAR, AXIN, AXOUT, CXIN_A, CXIN_B, CXOUT_A, CXOUT_B, TCUR)      \
    {                                                                            \
        h16x8 a1 = *(const h16x8*)&A[PAR][0][lane][0];                           \
        h16x8 a2 = *(const h16x8*)&A[PAR][1][lane][0];                           \
        h16x8 a3 = *(const h16x8*)&A[PAR][2][lane][0];                           \
        h16x8 a4 = *(const h16x8*)&A[PAR][3][lane][0];                           \
        _Pragma("unroll")                                                        \
        for (int jj = 0; jj < 4; ++jj) {                                         \
            const int j = JP[jj];                                                \
            AXOUT[j] = __builtin_amdgcn_mfma_f32_16x16x32_f16(xf_next, bh[j][0], biasC[j], 0, 0, 0); \
        }                                                                        \
        xf_next = (h16x8){ (_Float16)CXIN_A.x, (_Float16)CXIN_A.y, (_Float16)CXIN_A.z, (_Float16)CXIN_A.w, \
                           (_Float16)CXIN_B.x, (_Float16)CXIN_B.y, (_Float16)CXIN_B.z, (_Float16)CXIN_B.w }; \
        {                                                                        \
            const int tl = ((TCUR) + 3 < TT) ? ((TCUR) + 3) : (TT - 1);          \
            const float* p = xrow + (size_t)tl * FF;                             \
            CXOUT_A = *(const float4*)(p);                                       \
            CXOUT_B = *(const float4*)(p + 4);                                   \
        }                                                                        \
        f32x4 ac[4];                                                             \
        _Pragma("unroll")                                                        \
        for (int jj = 0; jj < 4; ++jj) {                                         \
            const int j = JP[jj];                                                \
            ac[j] = __builtin_amdgcn_mfma_f32_16x16x32_f16(a1, bh[j][1], AXIN[j], 0, 0, 0); \
        }                                                                        \
        _Pragma("unroll")                                                        \
        for (int jj = 0; jj < 4; ++jj) {                                         \
            const int j = JP[jj];                                                \
            ac[j] = __builtin_amdgcn_mfma_f32_16x16x32_f16(a2, bh[j][2], ac[j], 0, 0, 0); \
        }                                                                        \
        _Pragma("unroll")                                                        \
        for (int jj = 0; jj < 4; ++jj) {                                         \
            const int j = JP[jj];                                                \
            ac[j] = __builtin_amdgcn_mfma_f32_16x16x32_f16(a3, bh[j][3], ac[j], 0, 0, 0); \
        }                                                                        \
        _Pragma("unroll")                                                        \
        for (int jj = 0; jj < 4; ++jj) {                                         \
            const int j = JP[jj];                                                \
            ac[j] = __builtin_amdgcn_mfma_f32_16x16x32_f16(a4, bh[j][4], ac[j], 0, 0, 0); \
        }                                                                        \
        /* direct z reads (4, completion order); i,f,o scaled -L2E, g +2L2E */   \
        float z2 = ac[2][0];                                                     \
        float r2 = RCP(EX2(z2) + 1.f);          /* K2*tanh = K2 - 2K2*r2 */      \
        float z0 = ac[0][0];                                                     \
        float gi = RCP(EX2(z0) + 1.f);                                           \
        float T1 = fmaf(gi, K2, (-2.f * K2 * gi) * r2);  /* early: gi,r2 only */ \
        float z1 = ac[1][0];                                                     \
        float gf = RCP(EX2(z1) + 1.f);                                           \
        float z3 = ac[3][0];                                                     \
        float go = RCP(EX2(z3) + 1.f);                                           \
        float csn = fmaf(gf, cs, T1);           /* 1 op after gf */              \
        float rc  = RCP(EX2(csn) + 1.f);                                         \
        float hn  = fmaf(-2.f * go, rc, go);    /* go * tanh(c_new) */           \
        const bool upd = ((TCUR) < slq);                                         \
        cs = upd ? csn : cs;                                                     \
        hh = upd ? hn : hh;                                                      \
        A[(PAR) ^ 1][wkc][wslot][wj] = (_Float16)hh;                             \
        __syncthreads();                                                         \
    }

    int t = 0;
    for (; t + 1 < gmax; t += 2) {
        LSTM_STEP(0, accXa, accXb, cx0a, cx0b, cx1a, cx1b, t)
        LSTM_STEP(1, accXb, accXa, cx1a, cx1b, cx0a, cx0b, t + 1)
    }
    if (t < gmax) {          // gmax odd: one final even-parity step
        LSTM_STEP(0, accXa, accXb, cx0a, cx0b, cx1a, cx1b, t)
    }
#undef LSTM_STEP

    // epilogue: out[b] = h @ Wf + bf
    float p = hh * wfv;
    p += __shfl_down(p, 8, 16);
    p += __shfl_down(p, 4, 16);
    p += __shfl_down(p, 2, 16);
    p += __shfl_down(p, 1, 16);
    if (c == 0) atomicAdd(&outAcc[q], p);
    __syncthreads();
    if (tid < 4) out[b0 + tid] = outAcc[tid] + bfp[0];
}

extern "C" void kernel_launch(void* const* d_in, const int* in_sizes, int n_in,
                              void* d_out, int out_size, void* d_ws, size_t ws_size,
                              hipStream_t stream) {
    const float* x        = (const float*)d_in[0];
    const int*   seq_lens = (const int*)d_in[1];
    const float* W        = (const float*)d_in[2];
    const float* U        = (const float*)d_in[3];
    const float* bias     = (const float*)d_in[4];
    const float* Wf       = (const float*)d_in[5];
    const float* bfp      = (const float*)d_in[6];
    float* out = (float*)d_out;

    lstm_seq_kernel<<<dim3(64), dim3(512), 0, stream>>>(x, seq_lens, W, U, bias, Wf, bfp, out);
}

// Round 12
// 2190.124 us; speedup vs baseline: 1.0636x; 1.0636x over previous
//
#include <hip/hip_runtime.h>

// LSTM last-hidden + projection. B=256, T=4096, F=32, H=128, 4H=512.
// 64 WGs x 512 threads (8 waves, 2/SIMD, 1 WG/CU); WG g owns batches [4g,4g+4)
// at MFMA A-rows {0,4,8,12}. z(4x512) = [x_t|h](4x160) @ [W;U](160x512),
// mfma 16x16x32 f16.
// Model: makespan = 4096 x t_step. t_step ~1204cy (R14) = matrix pipe 776
// (40 mfma/SIMD @ ~19.4cy) + ~428 exposed serial (z->store spine ~275cy + L).
// Serial-tail instr ~25cy. MFMA C-dep latency ~250cy (R15 measurement!) ->
// dependent MFMA links need >=8 intervening slots at 2 waves/SIMD: the
// two-depth-2-chains + VALU-join structure is optimal (R15: depth-4 +97cy).
// HARD RULES (5 regressions' worth):
//  - step body BRANCH-FREE, no exec-mask dance (R11 +193cy; R14 -180cy);
//  - loop-carried regs written UNCONDITIONALLY only (R12 +265cy; selects ok);
//  - dependent MFMA pairs >=8 slots apart (R6, R15);
//  - single-variable changes only; revert on >2% regression.
// History: R5 2890; R6 REGRESS; R7 2780; R8 3600; R9 2455; R10 2371;
// R11 3160 REGRESS; R12 2824 REGRESS; R13 2363; R14 2056 = BEST;
// R15 2222 REGRESS (depth-4 C-dep stalls).
// R16 (this): R14 base + two tail-only dataflow cuts:
//  (1) FREE-RUNNING recurrence: batches are row-independent, so drop the
//      per-step freeze; cs=csn and store hn unconditionally (select-free
//      store path); snapshot hf=(t==slq-1)?hn:hf off-path for the epilogue.
//      Safe: cs worst-case grows linearly (finite); EX2(big)=inf -> rc=0 ->
//      tanh saturates; gf>=0 exact, cs finite -> no NaN.
//  (2) csn form u/v: u=fmaf(-2K2,r2,K2); v=gi*u; csn=fmaf(gf,cs,v) —
//      balances the act tree ~19-45cy better than R13's T1.

#define TT 4096
#define FF 32
#define HH 128
#define NG 512

typedef float f32x4 __attribute__((ext_vector_type(4)));
typedef _Float16 h16x8 __attribute__((ext_vector_type(8)));

#if __has_builtin(__builtin_amdgcn_exp2f)
#define EX2(v) __builtin_amdgcn_exp2f(v)
#else
#define EX2(v) exp2f(v)
#endif
#define RCP(v) __builtin_amdgcn_rcpf(v)

__global__ __launch_bounds__(512, 2)
void lstm_seq_kernel(const float* __restrict__ x,        // (B,T,F)
                     const int*   __restrict__ seq_lens, // (B)
                     const float* __restrict__ W,        // (F,4H)
                     const float* __restrict__ U,        // (H,4H)
                     const float* __restrict__ bias,     // (4H)
                     const float* __restrict__ Wf,       // (H)
                     const float* __restrict__ bfp,      // (1)
                     float* __restrict__ out)            // (B)
{
    // h-only A staging: A[par][kc-1][slot][j] == A[m=slot&15][k=kc*32+(slot>>4)*8+j]
    __shared__ _Float16 A[2][4][64][8];
    __shared__ float outAcc[4];

    const int tid  = threadIdx.x;
    const int lane = tid & 63;
    const int w    = tid >> 6;     // wave 0..7
    const int c    = lane & 15;    // n-col within tile
    const int q    = lane >> 4;    // quad 0..3 -> this lane's batch
    const int b0   = blockIdx.x * 4;
    const int hc   = w * 16 + c;   // this lane's LSTM cell (0..127)

    {
        _Float16* p = &A[0][0][0][0];
        for (int i = tid; i < 2 * 4 * 64 * 8; i += 512) p[i] = (_Float16)0.f;
        if (tid < 4) outAcc[tid] = 0.f;
    }

    const int sl0 = seq_lens[b0 + 0], sl1 = seq_lens[b0 + 1];
    const int sl2 = seq_lens[b0 + 2], sl3 = seq_lens[b0 + 3];
    const int gmax = max(max(sl0, sl1), max(sl2, sl3));
    const int slq  = seq_lens[b0 + q];

    const float L2E = 1.44269504f;      // log2(e)
    const float K2  = 2.88539008f;      // 2*log2(e)

    // gate issue order: g first (longest act chain), o last (needed last)
    const int JP[4] = {2, 0, 1, 3};

    // register-resident weights: wave w -> tiles {8j+w}, j = gate i,f,g,o; n = j*128+hc
    // B-frag: lane holds B[k = kc*32 + q*8 + e][n]
    // Columns pre-scaled: i,f,o by -L2E (sigmoid via bare exp2), g by +2*L2E.
    h16x8 bh[4][5];
    #pragma unroll
    for (int j = 0; j < 4; ++j) {
        const int n = j * 128 + hc;
        const float gsc = (j == 2) ? K2 : -L2E;
        #pragma unroll
        for (int kc = 0; kc < 5; ++kc) {
            #pragma unroll
            for (int e = 0; e < 8; ++e) {
                const int k = kc * 32 + q * 8 + e;
                float v = (k < FF) ? W[k * NG + n] : U[(k - FF) * NG + n];
                bh[j][kc][e] = (_Float16)(v * gsc);
            }
        }
    }

    // bias folded into accX's C operand (only element [0] is ever read), pre-scaled
    f32x4 biasC[4];
    #pragma unroll
    for (int j = 0; j < 4; ++j) {
        const float gsc = (j == 2) ? K2 : -L2E;
        const float bv = bias[j * HH + hc] * gsc;
        f32x4 t = {bv, bv, bv, bv};
        biasC[j] = t;
    }
    const float wfv = Wf[hc];
    const int kk    = FF + hc;                        // K-position of this h element
    const int wkc   = (kk >> 5) - 1;                  // 0..3
    const int wslot = ((kk >> 3) & 3) * 16 + 4 * q;   // batch q at row 4q
    const int wj    = kk & 7;

    // x A-fragment: lane supplies A[m=c][k=q*8+e]; rows m%4!=0 are never read,
    // and xrow is a VALID address for every lane (batch c>>2 in [0,4)) ->
    // loads are UNCONDITIONAL (no branch, no exec-mask dance).
    const float* xrow = x + (size_t)(b0 + (c >> 2)) * TT * FF + q * 8;

    const f32x4 zero4 = {0.f, 0.f, 0.f, 0.f};

    // ---- software pipeline state (no copies anywhere; double ping-pong) ----
    // accXa/accXb : z_x for alternating steps
    // xf_next     : cvt(x_{t+1}), feeds the head-issued z_x(t+1)
    // cx0/cx1     : raw x_{t+2} ping-pong pairs (written unconditionally)
    f32x4 accXa[4], accXb[4];
    h16x8 xf_next;
    {
        float4 xa = *(const float4*)(xrow);
        float4 xb = *(const float4*)(xrow + 4);
        h16x8 xf = { (_Float16)xa.x, (_Float16)xa.y, (_Float16)xa.z, (_Float16)xa.w,
                     (_Float16)xb.x, (_Float16)xb.y, (_Float16)xb.z, (_Float16)xb.w };
        #pragma unroll
        for (int j = 0; j < 4; ++j)
            accXa[j] = __builtin_amdgcn_mfma_f32_16x16x32_f16(xf, bh[j][0], biasC[j], 0, 0, 0);
    }
    {
        const float* p = xrow + (size_t)1 * FF;   // x_1
        float4 ya = *(const float4*)(p);
        float4 yb = *(const float4*)(p + 4);
        xf_next = (h16x8){ (_Float16)ya.x, (_Float16)ya.y, (_Float16)ya.z, (_Float16)ya.w,
                           (_Float16)yb.x, (_Float16)yb.y, (_Float16)yb.z, (_Float16)yb.w };
    }
    float4 cx0a, cx0b;                           // x_2 (pair 0)
    {
        const float* p = xrow + (size_t)2 * FF;
        cx0a = *(const float4*)(p);
        cx0b = *(const float4*)(p + 4);
    }
    float4 cx1a = {0,0,0,0}, cx1b = {0,0,0,0};   // pair 1: written in step 0 before read
    __syncthreads();

    float cs = 0.f;                 // 2*log2e * c, FREE-RUNNING (no freeze)
    float hf = 0.f;                 // snapshot of h at t = slq-1 (epilogue)

    // One LSTM step. PAR compile-time. AXIN consumed as chainP seed; AXOUT
    // (z_x for next step) + xf_next rotation + unconditional x-load (into
    // CXOUT pair) all issued at the HEAD inside the ds_read shadow.
    // Tail = join/act/ds_write (select-free store path); snapshot select
    // off-path. Step body is BRANCH-FREE.
#define LSTM_STEP(PAR, AXIN, AXOUT, CXIN_A, CXIN_B, CXOUT_A, CXOUT_B, TCUR)      \
    {                                                                            \
        h16x8 a1 = *(const h16x8*)&A[PAR][0][lane][0];                           \
        h16x8 a2 = *(const h16x8*)&A[PAR][1][lane][0];                           \
        h16x8 a3 = *(const h16x8*)&A[PAR][2][lane][0];                           \
        h16x8 a4 = *(const h16x8*)&A[PAR][3][lane][0];                           \
        _Pragma("unroll")                                                        \
        for (int jj = 0; jj < 4; ++jj) {                                         \
            const int j = JP[jj];                                                \
            AXOUT[j] = __builtin_amdgcn_mfma_f32_16x16x32_f16(xf_next, bh[j][0], biasC[j], 0, 0, 0); \
        }                                                                        \
        xf_next = (h16x8){ (_Float16)CXIN_A.x, (_Float16)CXIN_A.y, (_Float16)CXIN_A.z, (_Float16)CXIN_A.w, \
                           (_Float16)CXIN_B.x, (_Float16)CXIN_B.y, (_Float16)CXIN_B.z, (_Float16)CXIN_B.w }; \
        {                                                                        \
            const int tl = ((TCUR) + 3 < TT) ? ((TCUR) + 3) : (TT - 1);          \
            const float* p = xrow + (size_t)tl * FF;                             \
            CXOUT_A = *(const float4*)(p);                                       \
            CXOUT_B = *(const float4*)(p + 4);                                   \
        }                                                                        \
        f32x4 pc[4], qc[4];                                                      \
        _Pragma("unroll")                                                        \
        for (int jj = 0; jj < 4; ++jj) {                                         \
            const int j = JP[jj];                                                \
            qc[j] = __builtin_amdgcn_mfma_f32_16x16x32_f16(a3, bh[j][3], zero4, 0, 0, 0); \
        }                                                                        \
        _Pragma("unroll")                                                        \
        for (int jj = 0; jj < 4; ++jj) {                                         \
            const int j = JP[jj];                                                \
            pc[j] = __builtin_amdgcn_mfma_f32_16x16x32_f16(a1, bh[j][1], AXIN[j], 0, 0, 0); \
        }                                                                        \
        _Pragma("unroll")                                                        \
        for (int jj = 0; jj < 4; ++jj) {                                         \
            const int j = JP[jj];                                                \
            qc[j] = __builtin_amdgcn_mfma_f32_16x16x32_f16(a4, bh[j][4], qc[j], 0, 0, 0); \
        }                                                                        \
        _Pragma("unroll")                                                        \
        for (int jj = 0; jj < 4; ++jj) {                                         \
            const int j = JP[jj];                                                \
            pc[j] = __builtin_amdgcn_mfma_f32_16x16x32_f16(a2, bh[j][2], pc[j], 0, 0, 0); \
        }                                                                        \
        /* join in completion order; z pre-scaled: i,f,o by -L2E, g by +2L2E */  \
        float z2 = pc[2][0] + qc[2][0];                                          \
        float r2 = RCP(EX2(z2) + 1.f);          /* sigmoid-like, g gate */       \
        float u  = fmaf(-2.f * K2, r2, K2);     /* = K2*tanh(zg) */              \
        float z0 = pc[0][0] + qc[0][0];                                          \
        float gi = RCP(EX2(z0) + 1.f);                                           \
        float v  = gi * u;                                                       \
        float z1 = pc[1][0] + qc[1][0];                                          \
        float gf = RCP(EX2(z1) + 1.f);                                           \
        float z3 = pc[3][0] + qc[3][0];                                          \
        float go = RCP(EX2(z3) + 1.f);                                           \
        float csn = fmaf(gf, cs, v);            /* 1 op after gf */              \
        float rc  = RCP(EX2(csn) + 1.f);                                         \
        float hn  = fmaf(-2.f * go, rc, go);    /* go * tanh(c_new) */           \
        A[(PAR) ^ 1][wkc][wslot][wj] = (_Float16)hn;   /* unconditional */       \
        cs = csn;                               /* free-running */               \
        hf = ((TCUR) == slq - 1) ? hn : hf;     /* off-path snapshot */          \
        __syncthreads();                                                         \
    }

    int t = 0;
    for (; t + 1 < gmax; t += 2) {
        LSTM_STEP(0, accXa, accXb, cx0a, cx0b, cx1a, cx1b, t)
        LSTM_STEP(1, accXb, accXa, cx1a, cx1b, cx0a, cx0b, t + 1)
    }
    if (t < gmax) {          // gmax odd: one final even-parity step
        LSTM_STEP(0, accXa, accXb, cx0a, cx0b, cx1a, cx1b, t)
    }
#undef LSTM_STEP

    // epilogue: out[b] = h(slq) @ Wf + bf   (h snapshot at t = slq-1)
    float p = hf * wfv;
    p += __shfl_down(p, 8, 16);
    p += __shfl_down(p, 4, 16);
    p += __shfl_down(p, 2, 16);
    p += __shfl_down(p, 1, 16);
    if (c == 0) atomicAdd(&outAcc[q], p);
    __syncthreads();
    if (tid < 4) out[b0 + tid] = outAcc[tid] + bfp[0];
}

extern "C" void kernel_launch(void* const* d_in, const int* in_sizes, int n_in,
                              void* d_out, int out_size, void* d_ws, size_t ws_size,
                              hipStream_t stream) {
    const float* x        = (const float*)d_in[0];
    const int*   seq_lens = (const int*)d_in[1];
    const float* W        = (const float*)d_in[2];
    const float* U        = (const float*)d_in[3];
    const float* bias     = (const float*)d_in[4];
    const float* Wf       = (const float*)d_in[5];
    const float* bfp      = (const float*)d_in[6];
    float* out = (float*)d_out;

    lstm_seq_kernel<<<dim3(64), dim3(512), 0, stream>>>(x, seq_lens, W, U, bias, Wf, bfp, out);
}

// Round 13
// 2162.677 us; speedup vs baseline: 1.0771x; 1.0127x over previous
//
#include <hip/hip_runtime.h>

// LSTM last-hidden + projection. B=256, T=4096, F=32, H=128, 4H=512.
// 64 WGs x 512 threads (8 waves, 2/SIMD, 1 WG/CU); WG g owns batches [4g,4g+4)
// at MFMA A-rows {0,4,8,12}. z(4x512) = [x_t|h](4x160) @ [W;U](160x512),
// mfma 16x16x32 f16.
// Model: makespan = 4096 x t_step. t_step ~1204cy (R14) =
//   ds_read 120 + chain issue 621 (16 mfma x 2 waves @19.4) + L 250 +
//   act ~150 + store/barrier ~80; AXOUT at head adds ~35cy (155 issue vs
//   120 shadow). MFMA C-dep latency ~250cy (R15) -> two-depth-2-chains +
//   VALU join is optimal. Serial-tail op ~25cy but tail ops that overlap
//   the z-latency stall are FREE (R16: removing 3 tail ops = +0.5%).
// HARD RULES (6 regressions' worth):
//  - step body BRANCH-FREE, no exec-mask dance (R11 +193cy; R14 -180cy);
//  - loop-carried regs written UNCONDITIONALLY only (R12 +265cy; selects ok);
//  - dependent MFMA pairs >=8 slots apart (R6, R15 +97cy);
//  - single-variable changes; revert on >2% regression.
// History: R5 2890; R6 REGRESS; R7 2780; R8 3600; R9 2455; R10 2371;
// R11 3160 REGRESS; R12 2824 REGRESS; R13 2363; R14 2056 = BEST;
// R15 2222 REGRESS (depth-4 C-dep); R16 2067 neutral (tail already hidden).
// R17 (this): EXACT R14 + ONE change: AXOUT (z_x(t+1)) + xf_next rotation
// moved from the head to AFTER chain issue. Chains start at ds_read-complete
// (~120) instead of ~155; the 4 AXOUT mfmas issue into the idle mfma pipe
// during the 250cy z-wait; rotation cvts fill act-stall VALU slots. AXOUT
// completes ~990cy into step t, consumed at step t+1 ~+1300cy -> safe.

#define TT 4096
#define FF 32
#define HH 128
#define NG 512

typedef float f32x4 __attribute__((ext_vector_type(4)));
typedef _Float16 h16x8 __attribute__((ext_vector_type(8)));

#if __has_builtin(__builtin_amdgcn_exp2f)
#define EX2(v) __builtin_amdgcn_exp2f(v)
#else
#define EX2(v) exp2f(v)
#endif
#define RCP(v) __builtin_amdgcn_rcpf(v)

__global__ __launch_bounds__(512, 2)
void lstm_seq_kernel(const float* __restrict__ x,        // (B,T,F)
                     const int*   __restrict__ seq_lens, // (B)
                     const float* __restrict__ W,        // (F,4H)
                     const float* __restrict__ U,        // (H,4H)
                     const float* __restrict__ bias,     // (4H)
                     const float* __restrict__ Wf,       // (H)
                     const float* __restrict__ bfp,      // (1)
                     float* __restrict__ out)            // (B)
{
    // h-only A staging: A[par][kc-1][slot][j] == A[m=slot&15][k=kc*32+(slot>>4)*8+j]
    __shared__ _Float16 A[2][4][64][8];
    __shared__ float outAcc[4];

    const int tid  = threadIdx.x;
    const int lane = tid & 63;
    const int w    = tid >> 6;     // wave 0..7
    const int c    = lane & 15;    // n-col within tile
    const int q    = lane >> 4;    // quad 0..3 -> this lane's batch
    const int b0   = blockIdx.x * 4;
    const int hc   = w * 16 + c;   // this lane's LSTM cell (0..127)

    {
        _Float16* p = &A[0][0][0][0];
        for (int i = tid; i < 2 * 4 * 64 * 8; i += 512) p[i] = (_Float16)0.f;
        if (tid < 4) outAcc[tid] = 0.f;
    }

    const int sl0 = seq_lens[b0 + 0], sl1 = seq_lens[b0 + 1];
    const int sl2 = seq_lens[b0 + 2], sl3 = seq_lens[b0 + 3];
    const int gmax = max(max(sl0, sl1), max(sl2, sl3));
    const int slq  = seq_lens[b0 + q];

    const float L2E = 1.44269504f;      // log2(e)
    const float K2  = 2.88539008f;      // 2*log2(e)

    // gate issue order: g first (longest act chain), o last (needed last)
    const int JP[4] = {2, 0, 1, 3};

    // register-resident weights: wave w -> tiles {8j+w}, j = gate i,f,g,o; n = j*128+hc
    // B-frag: lane holds B[k = kc*32 + q*8 + e][n]
    // Columns pre-scaled: i,f,o by -L2E (sigmoid via bare exp2), g by +2*L2E.
    h16x8 bh[4][5];
    #pragma unroll
    for (int j = 0; j < 4; ++j) {
        const int n = j * 128 + hc;
        const float gsc = (j == 2) ? K2 : -L2E;
        #pragma unroll
        for (int kc = 0; kc < 5; ++kc) {
            #pragma unroll
            for (int e = 0; e < 8; ++e) {
                const int k = kc * 32 + q * 8 + e;
                float v = (k < FF) ? W[k * NG + n] : U[(k - FF) * NG + n];
                bh[j][kc][e] = (_Float16)(v * gsc);
            }
        }
    }

    // bias folded into accX's C operand (only element [0] is ever read), pre-scaled
    f32x4 biasC[4];
    #pragma unroll
    for (int j = 0; j < 4; ++j) {
        const float gsc = (j == 2) ? K2 : -L2E;
        const float bv = bias[j * HH + hc] * gsc;
        f32x4 t = {bv, bv, bv, bv};
        biasC[j] = t;
    }
    const float wfv = Wf[hc];
    const int kk    = FF + hc;                        // K-position of this h element
    const int wkc   = (kk >> 5) - 1;                  // 0..3
    const int wslot = ((kk >> 3) & 3) * 16 + 4 * q;   // batch q at row 4q
    const int wj    = kk & 7;

    // x A-fragment: lane supplies A[m=c][k=q*8+e]; rows m%4!=0 are never read,
    // and xrow is a VALID address for every lane (batch c>>2 in [0,4)) ->
    // loads are UNCONDITIONAL (no branch, no exec-mask dance).
    const float* xrow = x + (size_t)(b0 + (c >> 2)) * TT * FF + q * 8;

    const f32x4 zero4 = {0.f, 0.f, 0.f, 0.f};

    // ---- software pipeline state (no copies anywhere; double ping-pong) ----
    // accXa/accXb : z_x for alternating steps
    // xf_next     : cvt(x_{t+1}), feeds the tail-issued z_x(t+1)
    // cx0/cx1     : raw x_{t+2} ping-pong pairs (written unconditionally)
    f32x4 accXa[4], accXb[4];
    h16x8 xf_next;
    {
        float4 xa = *(const float4*)(xrow);
        float4 xb = *(const float4*)(xrow + 4);
        h16x8 xf = { (_Float16)xa.x, (_Float16)xa.y, (_Float16)xa.z, (_Float16)xa.w,
                     (_Float16)xb.x, (_Float16)xb.y, (_Float16)xb.z, (_Float16)xb.w };
        #pragma unroll
        for (int j = 0; j < 4; ++j)
            accXa[j] = __builtin_amdgcn_mfma_f32_16x16x32_f16(xf, bh[j][0], biasC[j], 0, 0, 0);
    }
    {
        const float* p = xrow + (size_t)1 * FF;   // x_1
        float4 ya = *(const float4*)(p);
        float4 yb = *(const float4*)(p + 4);
        xf_next = (h16x8){ (_Float16)ya.x, (_Float16)ya.y, (_Float16)ya.z, (_Float16)ya.w,
                           (_Float16)yb.x, (_Float16)yb.y, (_Float16)yb.z, (_Float16)yb.w };
    }
    float4 cx0a, cx0b;                           // x_2 (pair 0)
    {
        const float* p = xrow + (size_t)2 * FF;
        cx0a = *(const float4*)(p);
        cx0b = *(const float4*)(p + 4);
    }
    float4 cx1a = {0,0,0,0}, cx1b = {0,0,0,0};   // pair 1: written in step 0 before read
    __syncthreads();

    float cs = 0.f, hh = 0.f;   // cs = 2*log2e * c  (pre-scaled cell state)

    // One LSTM step. PAR compile-time. Head = {ds_reads, x-load into CXOUT,
    // 16 chain mfmas}. AXOUT (z_x for next step, from xf_next) + xf_next
    // rotation issue AFTER the chains, overlapping the 250cy z-latency wait
    // on the idle mfma pipe / act-stall VALU slots. Tail = join/act/selects/
    // ds_write. Step body is BRANCH-FREE.
#define LSTM_STEP(PAR, AXIN, AXOUT, CXIN_A, CXIN_B, CXOUT_A, CXOUT_B, TCUR)      \
    {                                                                            \
        h16x8 a1 = *(const h16x8*)&A[PAR][0][lane][0];                           \
        h16x8 a2 = *(const h16x8*)&A[PAR][1][lane][0];                           \
        h16x8 a3 = *(const h16x8*)&A[PAR][2][lane][0];                           \
        h16x8 a4 = *(const h16x8*)&A[PAR][3][lane][0];                           \
        {                                                                        \
            const int tl = ((TCUR) + 3 < TT) ? ((TCUR) + 3) : (TT - 1);          \
            const float* p = xrow + (size_t)tl * FF;                             \
            CXOUT_A = *(const float4*)(p);                                       \
            CXOUT_B = *(const float4*)(p + 4);                                   \
        }                                                                        \
        f32x4 pc[4], qc[4];                                                      \
        _Pragma("unroll")                                                        \
        for (int jj = 0; jj < 4; ++jj) {                                         \
            const int j = JP[jj];                                                \
            qc[j] = __builtin_amdgcn_mfma_f32_16x16x32_f16(a3, bh[j][3], zero4, 0, 0, 0); \
        }                                                                        \
        _Pragma("unroll")                                                        \
        for (int jj = 0; jj < 4; ++jj) {                                         \
            const int j = JP[jj];                                                \
            pc[j] = __builtin_amdgcn_mfma_f32_16x16x32_f16(a1, bh[j][1], AXIN[j], 0, 0, 0); \
        }                                                                        \
        _Pragma("unroll")                                                        \
        for (int jj = 0; jj < 4; ++jj) {                                         \
            const int j = JP[jj];                                                \
            qc[j] = __builtin_amdgcn_mfma_f32_16x16x32_f16(a4, bh[j][4], qc[j], 0, 0, 0); \
        }                                                                        \
        _Pragma("unroll")                                                        \
        for (int jj = 0; jj < 4; ++jj) {                                         \
            const int j = JP[jj];                                                \
            pc[j] = __builtin_amdgcn_mfma_f32_16x16x32_f16(a2, bh[j][2], pc[j], 0, 0, 0); \
        }                                                                        \
        /* z_x(t+1): issues into the idle mfma pipe during the z-wait */         \
        _Pragma("unroll")                                                        \
        for (int jj = 0; jj < 4; ++jj) {                                         \
            const int j = JP[jj];                                                \
            AXOUT[j] = __builtin_amdgcn_mfma_f32_16x16x32_f16(xf_next, bh[j][0], biasC[j], 0, 0, 0); \
        }                                                                        \
        xf_next = (h16x8){ (_Float16)CXIN_A.x, (_Float16)CXIN_A.y, (_Float16)CXIN_A.z, (_Float16)CXIN_A.w, \
                           (_Float16)CXIN_B.x, (_Float16)CXIN_B.y, (_Float16)CXIN_B.z, (_Float16)CXIN_B.w }; \
        /* join in completion order; z pre-scaled: i,f,o by -L2E, g by +2L2E */  \
        float z2 = pc[2][0] + qc[2][0];                                          \
        float r2 = RCP(EX2(z2) + 1.f);          /* K2*tanh = K2 - 2K2*r2 */      \
        float z0 = pc[0][0] + qc[0][0];                                          \
        float gi = RCP(EX2(z0) + 1.f);                                           \
        float T1 = fmaf(gi, K2, (-2.f * K2 * gi) * r2);  /* early: gi,r2 only */ \
        float z1 = pc[1][0] + qc[1][0];                                          \
        float gf = RCP(EX2(z1) + 1.f);                                           \
        float z3 = pc[3][0] + qc[3][0];                                          \
        float go = RCP(EX2(z3) + 1.f);                                           \
        float csn = fmaf(gf, cs, T1);           /* 1 op after gf */              \
        float rc  = RCP(EX2(csn) + 1.f);                                         \
        float hn  = fmaf(-2.f * go, rc, go);    /* go * tanh(c_new) */           \
        const bool upd = ((TCUR) < slq);                                         \
        cs = upd ? csn : cs;                                                     \
        hh = upd ? hn : hh;                                                      \
        A[(PAR) ^ 1][wkc][wslot][wj] = (_Float16)hh;                             \
        __syncthreads();                                                         \
    }

    int t = 0;
    for (; t + 1 < gmax; t += 2) {
        LSTM_STEP(0, accXa, accXb, cx0a, cx0b, cx1a, cx1b, t)
        LSTM_STEP(1, accXb, accXa, cx1a, cx1b, cx0a, cx0b, t + 1)
    }
    if (t < gmax) {          // gmax odd: one final even-parity step
        LSTM_STEP(0, accXa, accXb, cx0a, cx0b, cx1a, cx1b, t)
    }
#undef LSTM_STEP

    // epilogue: out[b] = h @ Wf + bf
    float p = hh * wfv;
    p += __shfl_down(p, 8, 16);
    p += __shfl_down(p, 4, 16);
    p += __shfl_down(p, 2, 16);
    p += __shfl_down(p, 1, 16);
    if (c == 0) atomicAdd(&outAcc[q], p);
    __syncthreads();
    if (tid < 4) out[b0 + tid] = outAcc[tid] + bfp[0];
}

extern "C" void kernel_launch(void* const* d_in, const int* in_sizes, int n_in,
                              void* d_out, int out_size, void* d_ws, size_t ws_size,
                              hipStream_t stream) {
    const float* x        = (const float*)d_in[0];
    const int*   seq_lens = (const int*)d_in[1];
    const float* W        = (const float*)d_in[2];
    const float* U        = (const float*)d_in[3];
    const float* bias     = (const float*)d_in[4];
    const float* Wf       = (const float*)d_in[5];
    const float* bfp      = (const float*)d_in[6];
    float* out = (float*)d_out;

    lstm_seq_kernel<<<dim3(64), dim3(512), 0, stream>>>(x, seq_lens, W, U, bias, Wf, bfp, out);
}